// Round 1
// baseline (1425.029 us; speedup 1.0000x reference)
//
#include <hip/hip_runtime.h>
#include <hip/hip_bf16.h>
#include <math.h>

#define NN 50000
#define EE 400000
#define TT 4
#define FD 128     // feature dim (both layers)
#define NPO 256    // xbuf row stride: [xl(128) | xr(128)]

__device__ inline float wsum(float v) {
  #pragma unroll
  for (int o = 32; o > 0; o >>= 1) v += __shfl_xor(v, o, 64);
  return v;
}

// ---------------- CSR build (shared by both layers) ----------------
__global__ void k_hist(const int* __restrict__ ei, int* __restrict__ cnt) {
  int idx = blockIdx.x * 256 + threadIdx.x;
  if (idx >= TT * EE) return;
  int t = idx / EE, e = idx - t * EE;
  int d = ei[(size_t)t * 2 * EE + EE + e];
  atomicAdd(&cnt[t * NN + d], 1);
}

__global__ void k_scan(const int* __restrict__ cnt, int* __restrict__ rowp) {
  __shared__ int sd[1024];
  __shared__ int carry;
  const int t = blockIdx.x, tid = threadIdx.x;
  if (tid == 0) carry = 0;
  __syncthreads();
  for (int base = 0; base < NN; base += 1024) {
    int i = base + tid;
    int v = (i < NN) ? cnt[t * NN + i] : 0;
    sd[tid] = v;
    __syncthreads();
    for (int off = 1; off < 1024; off <<= 1) {
      int x = (tid >= off) ? sd[tid - off] : 0;
      __syncthreads();
      sd[tid] += x;
      __syncthreads();
    }
    int incl = sd[tid];
    int c = carry;
    if (i < NN) rowp[t * (NN + 1) + i] = c + incl - v;   // exclusive scan
    __syncthreads();
    if (tid == 1023) carry = c + incl;
    __syncthreads();
  }
  if (tid == 0) rowp[t * (NN + 1) + NN] = carry;
}

__global__ void k_cursor(const int* __restrict__ rowp, int* __restrict__ cur) {
  int idx = blockIdx.x * 256 + threadIdx.x;
  if (idx >= TT * NN) return;
  int t = idx / NN, i = idx - t * NN;
  cur[idx] = rowp[t * (NN + 1) + i];
}

__global__ void k_scatter(const int* __restrict__ ei, int* __restrict__ cur,
                          int* __restrict__ col) {
  int idx = blockIdx.x * 256 + threadIdx.x;
  if (idx >= TT * EE) return;
  int t = idx / EE, e = idx - t * EE;
  int s = ei[(size_t)t * 2 * EE + e];
  int d = ei[(size_t)t * 2 * EE + EE + e];
  int pos = atomicAdd(&cur[t * NN + d], 1);
  col[t * EE + pos] = s;
}

// ---------------- f32 GEMM: out[:, 0:128] = A@Wl, out[:, 128:256] = A@Wr ----
// 128x128 tile, 8x8 per thread, K=128 in two 64-chunks. LDS [k][row]/[k][col].
__global__ __launch_bounds__(256, 2) void k_gemm(const float* __restrict__ A,
                                                 const float* __restrict__ Wl,
                                                 const float* __restrict__ Wr,
                                                 float* __restrict__ out) {
  __shared__ __align__(16) float As[64][132];
  __shared__ __align__(16) float Bs[64][132];
  const int m0 = blockIdx.x * 128;
  const float* B = blockIdx.y ? Wr : Wl;
  const int colbase = blockIdx.y * 128;
  const int tid = threadIdx.x;
  const int ty = tid >> 4, tx = tid & 15;
  float acc[8][8];
  #pragma unroll
  for (int i = 0; i < 8; ++i)
    #pragma unroll
    for (int j = 0; j < 8; ++j) acc[i][j] = 0.f;

  for (int kc = 0; kc < 128; kc += 64) {
    {
      int r = tid >> 4;
      const int k4 = (tid & 15) * 4;
      #pragma unroll
      for (int it = 0; it < 8; ++it, r += 16) {
        int row = m0 + r;
        float4 v = make_float4(0.f, 0.f, 0.f, 0.f);
        if (row < NN) v = *(const float4*)(A + (size_t)row * FD + kc + k4);
        As[k4 + 0][r] = v.x; As[k4 + 1][r] = v.y;
        As[k4 + 2][r] = v.z; As[k4 + 3][r] = v.w;
      }
      int k = tid >> 5;
      const int c4 = (tid & 31) * 4;
      #pragma unroll
      for (int it = 0; it < 8; ++it, k += 8) {
        *(float4*)&Bs[k][c4] = *(const float4*)(B + (size_t)(kc + k) * FD + c4);
      }
    }
    __syncthreads();
    #pragma unroll 8
    for (int k = 0; k < 64; ++k) {
      float a[8], b[8];
      *(float4*)&a[0] = *(const float4*)&As[k][ty * 8];
      *(float4*)&a[4] = *(const float4*)&As[k][ty * 8 + 4];
      *(float4*)&b[0] = *(const float4*)&Bs[k][tx * 8];
      *(float4*)&b[4] = *(const float4*)&Bs[k][tx * 8 + 4];
      #pragma unroll
      for (int i = 0; i < 8; ++i)
        #pragma unroll
        for (int j = 0; j < 8; ++j) acc[i][j] = fmaf(a[i], b[j], acc[i][j]);
    }
    __syncthreads();
  }
  #pragma unroll
  for (int i = 0; i < 8; ++i) {
    int row = m0 + ty * 8 + i;
    if (row < NN) {
      float* o = out + (size_t)row * NPO + colbase + tx * 8;
      *(float4*)o = make_float4(acc[i][0], acc[i][1], acc[i][2], acc[i][3]);
      *(float4*)(o + 4) = make_float4(acc[i][4], acc[i][5], acc[i][6], acc[i][7]);
    }
  }
}

// ---------------- GATv2 aggregation: one wave per destination ----------------
// Online softmax over {self loop} ∪ CSR incoming edges. Lane holds channel
// `lane` of head0 and `64+lane` of head1.
__global__ __launch_bounds__(256) void k_aggregate(
    const float* __restrict__ xf, const int* __restrict__ col,
    const int* __restrict__ rowp, const float* __restrict__ att,
    const float* __restrict__ bias, float* __restrict__ hout,
    const int initFlag) {
  const int lane = threadIdx.x & 63;
  const int d = blockIdx.x * 4 + (threadIdx.x >> 6);
  if (d >= NN) return;
  const float* xd = xf + (size_t)d * NPO;
  const float xr_a = xd[128 + lane], xr_b = xd[192 + lane];
  const float xl_a = xd[lane],       xl_b = xd[64 + lane];
  const float att_a = att[lane],     att_b = att[64 + lane];
  // self-loop edge initializes running state
  float va = xl_a + xr_a; va = va > 0.f ? va : 0.2f * va;
  float vb = xl_b + xr_b; vb = vb > 0.f ? vb : 0.2f * vb;
  float m0 = wsum(att_a * va), m1 = wsum(att_b * vb);
  float den0 = 1.f, den1 = 1.f;
  float acc_a = xl_a, acc_b = xl_b;
  const int beg = rowp[d], end = rowp[d + 1];
  for (int e = beg; e < end; ++e) {
    const int s = col[e];
    const float* xs = xf + (size_t)s * NPO;
    const float xla = xs[lane], xlb = xs[64 + lane];
    va = xla + xr_a; va = va > 0.f ? va : 0.2f * va;
    vb = xlb + xr_b; vb = vb > 0.f ? vb : 0.2f * vb;
    const float p0 = wsum(att_a * va), p1 = wsum(att_b * vb);
    const float nm0 = fmaxf(m0, p0), nm1 = fmaxf(m1, p1);
    const float sc0 = __expf(m0 - nm0), w0 = __expf(p0 - nm0);
    const float sc1 = __expf(m1 - nm1), w1 = __expf(p1 - nm1);
    den0 = den0 * sc0 + w0; acc_a = acc_a * sc0 + w0 * xla;
    den1 = den1 * sc1 + w1; acc_b = acc_b * sc1 + w1 * xlb;
    m0 = nm0; m1 = nm1;
  }
  const float oa = acc_a / den0 + bias[lane];
  const float ob = acc_b / den1 + bias[64 + lane];
  float* hp = hout + (size_t)d * FD;
  if (initFlag) { hp[lane] = oa; hp[64 + lane] = ob; }
  else          { hp[lane] += oa; hp[64 + lane] += ob; }
}

__global__ void k_relu(float* __restrict__ h, int n) {
  int i = blockIdx.x * 256 + threadIdx.x;
  if (i < n) h[i] = fmaxf(h[i], 0.f);
}

// ---------------- MLP head: [N,128] -> relu(@W1+b1) [N,8] -> @W2+b2 [N,10] ---
__global__ __launch_bounds__(256) void k_mlp(const float* __restrict__ h,
                                             const float* __restrict__ W1,
                                             const float* __restrict__ b1,
                                             const float* __restrict__ W2,
                                             const float* __restrict__ b2,
                                             float* __restrict__ out) {
  __shared__ float sW1[128 * 8];
  __shared__ float sW2[8 * 10];
  __shared__ float sb1[8], sb2[10];
  for (int i = threadIdx.x; i < 1024; i += 256) sW1[i] = W1[i];
  if (threadIdx.x < 80) sW2[threadIdx.x] = W2[threadIdx.x];
  if (threadIdx.x < 8)  sb1[threadIdx.x] = b1[threadIdx.x];
  if (threadIdx.x < 10) sb2[threadIdx.x] = b2[threadIdx.x];
  __syncthreads();
  const int n = blockIdx.x * 256 + threadIdx.x;
  if (n >= NN) return;
  const float* hn = h + (size_t)n * FD;
  float z[8];
  #pragma unroll
  for (int j = 0; j < 8; ++j) z[j] = sb1[j];
  for (int k = 0; k < FD; k += 4) {
    float4 hv = *(const float4*)(hn + k);
    #pragma unroll
    for (int j = 0; j < 8; ++j) {
      z[j] += hv.x * sW1[(k + 0) * 8 + j] + hv.y * sW1[(k + 1) * 8 + j]
            + hv.z * sW1[(k + 2) * 8 + j] + hv.w * sW1[(k + 3) * 8 + j];
    }
  }
  #pragma unroll
  for (int j = 0; j < 8; ++j) z[j] = fmaxf(z[j], 0.f);
  float o[10];
  #pragma unroll
  for (int c = 0; c < 10; ++c) o[c] = sb2[c];
  #pragma unroll
  for (int j = 0; j < 8; ++j)
    #pragma unroll
    for (int c = 0; c < 10; ++c) o[c] += z[j] * sW2[j * 10 + c];
  float* op = out + (size_t)n * 10;
  #pragma unroll
  for (int c = 0; c < 10; ++c) op[c] = o[c];
}

extern "C" void kernel_launch(void* const* d_in, const int* in_sizes, int n_in,
                              void* d_out, int out_size, void* d_ws, size_t ws_size,
                              hipStream_t stream) {
  const float* x    = (const float*)d_in[0];
  const int*   ei   = (const int*)d_in[1];
  const float* Wl1  = (const float*)d_in[2];
  const float* Wr1  = (const float*)d_in[3];
  const float* att1 = (const float*)d_in[4];
  const float* b1   = (const float*)d_in[5];
  const float* Wl2  = (const float*)d_in[6];
  const float* Wr2  = (const float*)d_in[7];
  const float* att2 = (const float*)d_in[8];
  const float* b2   = (const float*)d_in[9];
  const float* Wi1  = (const float*)d_in[10];
  const float* bi1  = (const float*)d_in[11];
  const float* Wi2  = (const float*)d_in[12];
  const float* bi2  = (const float*)d_in[13];
  float* out = (float*)d_out;

  char* ws = (char*)d_ws;
  size_t off = 0;
  auto alloc = [&](size_t bytes) {
    void* p = ws + off;
    off = (off + bytes + 255) & ~(size_t)255;
    return p;
  };
  float* xbuf = (float*)alloc((size_t)NN * NPO * 4);      // 51.2 MB
  float* h1   = (float*)alloc((size_t)NN * FD * 4);       // 25.6 MB
  float* h2   = (float*)alloc((size_t)NN * FD * 4);       // 25.6 MB
  int*   col  = (int*)alloc((size_t)TT * EE * 4);         // 6.4 MB
  int*   rowp = (int*)alloc((size_t)TT * (NN + 1) * 4);
  int*   cur  = (int*)alloc((size_t)TT * NN * 4);

  // --- CSR build (identical for both layers) ---
  hipMemsetAsync(cur, 0, (size_t)TT * NN * 4, stream);
  k_hist<<<(TT * EE + 255) / 256, 256, 0, stream>>>(ei, cur);
  k_scan<<<TT, 1024, 0, stream>>>(cur, rowp);
  k_cursor<<<(TT * NN + 255) / 256, 256, 0, stream>>>(rowp, cur);
  k_scatter<<<(TT * EE + 255) / 256, 256, 0, stream>>>(ei, cur, col);

  dim3 ggrid(391, 2);
  // --- layer 1 ---
  for (int t = 0; t < TT; ++t) {
    k_gemm<<<ggrid, 256, 0, stream>>>(x, Wl1 + t * 16384, Wr1 + t * 16384, xbuf);
    k_aggregate<<<(NN + 3) / 4, 256, 0, stream>>>(
        xbuf, col + t * EE, rowp + t * (NN + 1), att1 + t * 128, b1 + t * 128,
        h1, t == 0);
  }
  k_relu<<<(NN * FD + 255) / 256, 256, 0, stream>>>(h1, NN * FD);
  // --- layer 2 ---
  for (int t = 0; t < TT; ++t) {
    k_gemm<<<ggrid, 256, 0, stream>>>(h1, Wl2 + t * 16384, Wr2 + t * 16384, xbuf);
    k_aggregate<<<(NN + 3) / 4, 256, 0, stream>>>(
        xbuf, col + t * EE, rowp + t * (NN + 1), att2 + t * 128, b2 + t * 128,
        h2, t == 0);
  }
  k_relu<<<(NN * FD + 255) / 256, 256, 0, stream>>>(h2, NN * FD);
  // --- MLP head ---
  k_mlp<<<(NN + 255) / 256, 256, 0, stream>>>(h2, Wi1, bi1, Wi2, bi2, out);
}

// Round 3
// 796.563 us; speedup vs baseline: 1.7890x; 1.7890x over previous
//
#include <hip/hip_runtime.h>
#include <hip/hip_bf16.h>
#include <math.h>

#define NN 50000
#define EE 400000
#define TT 4
#define FD 128
#define RPS 50004        // rowp stride (padded to 16B alignment)
#define NBKT 196         // buckets per type = ceil(NN/256)
#define BCAP 4096        // fixed capacity per bucket (mean fill ~2040)

typedef __attribute__((ext_vector_type(8))) short bf16x8;
typedef __attribute__((ext_vector_type(4))) float f32x4;

__device__ inline float bf2f(unsigned short u) {
  union { unsigned int i; float f; } x; x.i = ((unsigned int)u) << 16; return x.f;
}
__device__ inline unsigned short f2bf(float f) {
  __hip_bfloat16 h = __float2bfloat16(f);
  unsigned short u; __builtin_memcpy(&u, &h, 2); return u;
}
__device__ inline float gsum(float v) {   // sum within each 32-lane half-wave
  v += __shfl_xor(v, 1);
  v += __shfl_xor(v, 2);
  v += __shfl_xor(v, 4);
  v += __shfl_xor(v, 8);
  v += __shfl_xor(v, 16);
  return v;
}

// ---------- weight pack: W[k][c] f32 -> bf16 fragments in MFMA order ----------
// region R = ((layer*TT + t)*2 + lr), 16384 bf16 per region.
__global__ void k_cvtW(const float* __restrict__ Wl1, const float* __restrict__ Wr1,
                       const float* __restrict__ Wl2, const float* __restrict__ Wr2,
                       unsigned short* __restrict__ Bpack) {
  const int idx = blockIdx.x * 256 + threadIdx.x;      // 2*4*2*16384 = 262144
  const int R = idx >> 14;
  const int kc = idx & 16383;
  const int lr = R & 1, t = (R >> 1) & 3, layer = R >> 3;
  const float* W = layer ? (lr ? Wr2 : Wl2) : (lr ? Wr1 : Wl1);
  const float v = W[t * 16384 + kc];
  const int k = kc >> 7, c = kc & 127;
  const int nt = c >> 4, ks = k >> 5, g = (k >> 3) & 3, j = k & 7;
  const int lane = g * 16 + (c & 15);
  Bpack[(size_t)R * 16384 + ((nt * 4 + ks) * 64 + lane) * 8 + j] = f2bf(v);
}

// ---------- A split: f32 -> (hi, lo) bf16, optional fused relu ----------
__global__ void k_cvtA(const float* __restrict__ src, unsigned short* __restrict__ ahi,
                       unsigned short* __restrict__ alo, const int relu) {
  const int idx = blockIdx.x * 256 + threadIdx.x;      // NN*FD/4 = 1,600,000
  float4 v = ((const float4*)src)[idx];
  if (relu) {
    v.x = fmaxf(v.x, 0.f); v.y = fmaxf(v.y, 0.f);
    v.z = fmaxf(v.z, 0.f); v.w = fmaxf(v.w, 0.f);
  }
  const unsigned short h0 = f2bf(v.x), h1 = f2bf(v.y), h2 = f2bf(v.z), h3 = f2bf(v.w);
  const unsigned short l0 = f2bf(v.x - bf2f(h0)), l1 = f2bf(v.y - bf2f(h1));
  const unsigned short l2 = f2bf(v.z - bf2f(h2)), l3 = f2bf(v.w - bf2f(h3));
  uint2 hv, lv;
  hv.x = (unsigned)h0 | ((unsigned)h1 << 16); hv.y = (unsigned)h2 | ((unsigned)h3 << 16);
  lv.x = (unsigned)l0 | ((unsigned)l1 << 16); lv.y = (unsigned)l2 | ((unsigned)l3 << 16);
  ((uint2*)ahi)[idx] = hv;
  ((uint2*)alo)[idx] = lv;
}

// ---------- MFMA GEMM: [N,128] x [128,256] -> xl bf16 | xr bf16 ----------
// block = 128 thr (2 waves), wave owns 32 rows x 256 cols; no LDS.
__global__ __launch_bounds__(128) void k_gemm(
    const unsigned short* __restrict__ Ahi, const unsigned short* __restrict__ Alo,
    const unsigned short* __restrict__ Bpt,
    unsigned short* __restrict__ xl, unsigned short* __restrict__ xr) {
  const int tid = threadIdx.x;
  const int lane = tid & 63;
  const int w = tid >> 6;
  const int rh = lane & 15, g = lane >> 4;
  const int m0 = blockIdx.x * 64 + w * 32;
  f32x4 acc[2][16];
  #pragma unroll
  for (int a = 0; a < 2; ++a)
    #pragma unroll
    for (int b = 0; b < 16; ++b) acc[a][b] = (f32x4){0.f, 0.f, 0.f, 0.f};
  int r0 = m0 + rh;      if (r0 > NN - 1) r0 = NN - 1;
  int r1 = m0 + 16 + rh; if (r1 > NN - 1) r1 = NN - 1;
  #pragma unroll
  for (int ks = 0; ks < 4; ++ks) {
    const int ko = ks * 32 + g * 8;
    const bf16x8 ah0 = *(const bf16x8*)(Ahi + (size_t)r0 * FD + ko);
    const bf16x8 al0 = *(const bf16x8*)(Alo + (size_t)r0 * FD + ko);
    const bf16x8 ah1 = *(const bf16x8*)(Ahi + (size_t)r1 * FD + ko);
    const bf16x8 al1 = *(const bf16x8*)(Alo + (size_t)r1 * FD + ko);
    #pragma unroll
    for (int nt = 0; nt < 16; ++nt) {
      const bf16x8 b = *(const bf16x8*)(Bpt + (nt >> 3) * 16384 +
                                        (((nt & 7) * 4 + ks) * 64 + lane) * 8);
      acc[0][nt] = __builtin_amdgcn_mfma_f32_16x16x32_bf16(ah0, b, acc[0][nt], 0, 0, 0);
      acc[0][nt] = __builtin_amdgcn_mfma_f32_16x16x32_bf16(al0, b, acc[0][nt], 0, 0, 0);
      acc[1][nt] = __builtin_amdgcn_mfma_f32_16x16x32_bf16(ah1, b, acc[1][nt], 0, 0, 0);
      acc[1][nt] = __builtin_amdgcn_mfma_f32_16x16x32_bf16(al1, b, acc[1][nt], 0, 0, 0);
    }
  }
  #pragma unroll
  for (int mt = 0; mt < 2; ++mt)
    #pragma unroll
    for (int nt = 0; nt < 16; ++nt) {
      unsigned short* op = (nt < 8) ? xl : xr;
      const int cb = (nt & 7) * 16 + rh;
      #pragma unroll
      for (int r = 0; r < 4; ++r) {
        const int row = m0 + mt * 16 + g * 4 + r;   // m89-verified C/D mapping
        if (row < NN) op[(size_t)row * FD + cb] = f2bf(acc[mt][nt][r]);
      }
    }
}

// ---------- CSR build ----------
__global__ void k_hist2(const int* __restrict__ ei, int* __restrict__ cnt) {
  const int idx = blockIdx.x * 256 + threadIdx.x;
  if (idx >= TT * EE) return;
  const int t = idx / EE, e = idx - t * EE;
  const int dd = ei[(size_t)t * 2 * EE + EE + e];
  atomicAdd(&cnt[t * NN + dd], 1);
}

__global__ void k_scan_p1(const int* __restrict__ cnt, int* __restrict__ rowp,
                          int* __restrict__ psum) {
  __shared__ int s[512];
  const int t = blockIdx.y, chunk = blockIdx.x, tid = threadIdx.x;
  const int base = chunk * 2048 + tid * 4;
  int4 v = make_int4(0, 0, 0, 0);
  if (base < NN) v = *(const int4*)(cnt + (size_t)t * NN + base);
  const int tot = v.x + v.y + v.z + v.w;
  s[tid] = tot;
  __syncthreads();
  #pragma unroll
  for (int off = 1; off < 512; off <<= 1) {
    const int a = (tid >= off) ? s[tid - off] : 0;
    __syncthreads();
    s[tid] += a;
    __syncthreads();
  }
  const int excl = s[tid] - tot;
  if (base < NN) {
    int* rp = rowp + (size_t)t * RPS + base;
    rp[0] = excl; rp[1] = excl + v.x; rp[2] = excl + v.x + v.y; rp[3] = excl + v.x + v.y + v.z;
  }
  if (tid == 511) psum[t * 25 + chunk] = s[511];
}

__global__ void k_scan_p2(int* __restrict__ psum) {
  __shared__ int s[128];
  const int tid = threadIdx.x;   // 128
  const int v = (tid < 100) ? psum[tid] : 0;
  s[tid] = v;
  __syncthreads();
  const int seg = (tid / 25) * 25;
  #pragma unroll
  for (int off = 1; off < 32; off <<= 1) {
    const int a = (tid < 100 && tid - off >= seg) ? s[tid - off] : 0;
    __syncthreads();
    s[tid] += a;
    __syncthreads();
  }
  if (tid < 100) psum[tid] = s[tid] - v;   // exclusive chunk offsets
}

__global__ void k_scan_p3(const int* __restrict__ psum, int* __restrict__ rowp) {
  const int t = blockIdx.y, chunk = blockIdx.x, tid = threadIdx.x;
  const int add = psum[t * 25 + chunk];
  const int base = chunk * 2048 + tid * 4;
  if (base < NN) {
    int* rp = rowp + (size_t)t * RPS + base;
    int4 v = *(int4*)rp;
    v.x += add; v.y += add; v.z += add; v.w += add;
    *(int4*)rp = v;
  }
  if (chunk == 0 && tid == 0) rowp[(size_t)t * RPS + NN] = EE;
}

// bucket binning: 4096-edge chunk per block, LDS ranks, contiguous runs out.
__global__ __launch_bounds__(256) void k_bucket(const int* __restrict__ ei,
                                                int* __restrict__ bcur,
                                                unsigned int* __restrict__ ebuf) {
  __shared__ int lcnt[NBKT], lbase[NBKT];
  const int t = blockIdx.y, tid = threadIdx.x;
  const int cbase = blockIdx.x * 4096;
  if (tid < NBKT) lcnt[tid] = 0;
  __syncthreads();
  const int* srcp = ei + (size_t)t * 2 * EE;
  const int* dstp = srcp + EE;
  unsigned int pk[16]; int rk[16];
  #pragma unroll
  for (int i = 0; i < 16; ++i) {
    const int e = cbase + i * 256 + tid;
    rk[i] = -1;
    if (e < EE) {
      const int s = srcp[e], dd = dstp[e];
      const int b = dd >> 8;
      pk[i] = ((unsigned)dd << 16) | (unsigned)s;
      rk[i] = (atomicAdd(&lcnt[b], 1) << 8) | b;
    }
  }
  __syncthreads();
  if (tid < NBKT && lcnt[tid] > 0) lbase[tid] = atomicAdd(&bcur[t * NBKT + tid], lcnt[tid]);
  __syncthreads();
  #pragma unroll
  for (int i = 0; i < 16; ++i) {
    if (rk[i] >= 0) {
      const int b = rk[i] & 255, r = rk[i] >> 8;
      ebuf[((size_t)t * NBKT + b) * BCAP + lbase[b] + r] = pk[i];
    }
  }
}

// fine scatter: one block per (bucket, type); LDS cursors, exclusive col window.
__global__ __launch_bounds__(256) void k_scatter2(const unsigned int* __restrict__ ebuf,
                                                  const int* __restrict__ bcur,
                                                  const int* __restrict__ rowp,
                                                  int* __restrict__ col) {
  __shared__ int lcur[256];
  const int b = blockIdx.x, t = blockIdx.y, tid = threadIdx.x;
  const int d0 = b << 8;
  const int nd = (NN - d0 < 256) ? (NN - d0) : 256;
  if (tid < nd) lcur[tid] = rowp[(size_t)t * RPS + d0 + tid];
  __syncthreads();
  const int cnt = bcur[t * NBKT + b];
  const unsigned int* eb = ebuf + ((size_t)t * NBKT + b) * BCAP;
  for (int j = tid; j < cnt; j += 256) {
    const unsigned int u = eb[j];
    const int dd = u >> 16, s = u & 0xFFFF;
    const int pos = atomicAdd(&lcur[dd - d0], 1);
    col[(size_t)t * EE + pos] = s;
  }
}

// ---------- GATv2 aggregation: one wave per dst, online softmax ----------
// lane owns flat channels {2*lane, 2*lane+1}; lanes 0-31 = head0, 32-63 = head1.
__global__ __launch_bounds__(256) void k_agg(
    const unsigned short* __restrict__ xl, const unsigned short* __restrict__ xr,
    const int* __restrict__ col, const int* __restrict__ rowp,
    const float* __restrict__ att, const float* __restrict__ bias,
    float* __restrict__ hout, const int initFlag) {
  const int lane = threadIdx.x & 63;
  const int d = blockIdx.x * 4 + (threadIdx.x >> 6);
  if (d >= NN) return;
  const float2 av = ((const float2*)att)[lane];
  unsigned int ur, ulp;
  __builtin_memcpy(&ur, xr + (size_t)d * FD + 2 * lane, 4);
  __builtin_memcpy(&ulp, xl + (size_t)d * FD + 2 * lane, 4);
  const float xr0 = bf2f((unsigned short)(ur & 0xFFFF)), xr1 = bf2f((unsigned short)(ur >> 16));
  const float sl0 = bf2f((unsigned short)(ulp & 0xFFFF)), sl1 = bf2f((unsigned short)(ulp >> 16));
  float v0 = sl0 + xr0; v0 = v0 > 0.f ? v0 : 0.2f * v0;
  float v1 = sl1 + xr1; v1 = v1 > 0.f ? v1 : 0.2f * v1;
  float m = gsum(av.x * v0 + av.y * v1);     // self-loop score
  float den = 1.f, ac0 = sl0, ac1 = sl1;
  int e = rowp[d];
  const int end = rowp[d + 1];
  for (; e + 1 < end; e += 2) {
    const int s0 = col[e], s1 = col[e + 1];
    unsigned int u0, u1;
    __builtin_memcpy(&u0, xl + (size_t)s0 * FD + 2 * lane, 4);
    __builtin_memcpy(&u1, xl + (size_t)s1 * FD + 2 * lane, 4);
    const float x00 = bf2f((unsigned short)(u0 & 0xFFFF)), x01 = bf2f((unsigned short)(u0 >> 16));
    const float x10 = bf2f((unsigned short)(u1 & 0xFFFF)), x11 = bf2f((unsigned short)(u1 >> 16));
    float a0 = x00 + xr0; a0 = a0 > 0.f ? a0 : 0.2f * a0;
    float a1 = x01 + xr1; a1 = a1 > 0.f ? a1 : 0.2f * a1;
    float b0 = x10 + xr0; b0 = b0 > 0.f ? b0 : 0.2f * b0;
    float b1 = x11 + xr1; b1 = b1 > 0.f ? b1 : 0.2f * b1;
    const float q0 = gsum(av.x * a0 + av.y * a1);
    const float q1 = gsum(av.x * b0 + av.y * b1);
    const float nm = fmaxf(m, fmaxf(q0, q1));
    const float sc = __expf(m - nm), w0 = __expf(q0 - nm), w1 = __expf(q1 - nm);
    den = den * sc + w0 + w1;
    ac0 = ac0 * sc + w0 * x00 + w1 * x10;
    ac1 = ac1 * sc + w0 * x01 + w1 * x11;
    m = nm;
  }
  if (e < end) {
    const int s0 = col[e];
    unsigned int u0;
    __builtin_memcpy(&u0, xl + (size_t)s0 * FD + 2 * lane, 4);
    const float x00 = bf2f((unsigned short)(u0 & 0xFFFF)), x01 = bf2f((unsigned short)(u0 >> 16));
    float a0 = x00 + xr0; a0 = a0 > 0.f ? a0 : 0.2f * a0;
    float a1 = x01 + xr1; a1 = a1 > 0.f ? a1 : 0.2f * a1;
    const float q0 = gsum(av.x * a0 + av.y * a1);
    const float nm = fmaxf(m, q0);
    const float sc = __expf(m - nm), w0 = __expf(q0 - nm);
    den = den * sc + w0;
    ac0 = ac0 * sc + w0 * x00;
    ac1 = ac1 * sc + w0 * x01;
  }
  const float2 bv = ((const float2*)bias)[lane];
  const float o0 = ac0 / den + bv.x, o1 = ac1 / den + bv.y;
  float2* hp = (float2*)(hout + (size_t)d * FD) + lane;
  if (initFlag) {
    *hp = make_float2(o0, o1);
  } else {
    const float2 h = *hp;
    *hp = make_float2(h.x + o0, h.y + o1);
  }
}

// ---------- MLP head (relu on h fused) ----------
__global__ __launch_bounds__(256) void k_mlp(const float* __restrict__ h,
                                             const float* __restrict__ W1,
                                             const float* __restrict__ b1,
                                             const float* __restrict__ W2,
                                             const float* __restrict__ b2,
                                             float* __restrict__ out) {
  __shared__ float sW1[128 * 8];
  __shared__ float sW2[8 * 10];
  __shared__ float sb1[8], sb2[10];
  for (int i = threadIdx.x; i < 1024; i += 256) sW1[i] = W1[i];
  if (threadIdx.x < 80) sW2[threadIdx.x] = W2[threadIdx.x];
  if (threadIdx.x < 8)  sb1[threadIdx.x] = b1[threadIdx.x];
  if (threadIdx.x < 10) sb2[threadIdx.x] = b2[threadIdx.x];
  __syncthreads();
  const int n = blockIdx.x * 256 + threadIdx.x;
  if (n >= NN) return;
  const float* hn = h + (size_t)n * FD;
  float z[8];
  #pragma unroll
  for (int j = 0; j < 8; ++j) z[j] = sb1[j];
  for (int k = 0; k < FD; k += 4) {
    float4 hv = *(const float4*)(hn + k);
    hv.x = fmaxf(hv.x, 0.f); hv.y = fmaxf(hv.y, 0.f);
    hv.z = fmaxf(hv.z, 0.f); hv.w = fmaxf(hv.w, 0.f);
    #pragma unroll
    for (int j = 0; j < 8; ++j) {
      z[j] += hv.x * sW1[(k + 0) * 8 + j] + hv.y * sW1[(k + 1) * 8 + j]
            + hv.z * sW1[(k + 2) * 8 + j] + hv.w * sW1[(k + 3) * 8 + j];
    }
  }
  #pragma unroll
  for (int j = 0; j < 8; ++j) z[j] = fmaxf(z[j], 0.f);
  float o[10];
  #pragma unroll
  for (int c = 0; c < 10; ++c) o[c] = sb2[c];
  #pragma unroll
  for (int j = 0; j < 8; ++j)
    #pragma unroll
    for (int c = 0; c < 10; ++c) o[c] += z[j] * sW2[j * 10 + c];
  float* op = out + (size_t)n * 10;
  #pragma unroll
  for (int c = 0; c < 10; ++c) op[c] = o[c];
}

extern "C" void kernel_launch(void* const* d_in, const int* in_sizes, int n_in,
                              void* d_out, int out_size, void* d_ws, size_t ws_size,
                              hipStream_t stream) {
  const float* x    = (const float*)d_in[0];
  const int*   ei   = (const int*)d_in[1];
  const float* Wl1  = (const float*)d_in[2];
  const float* Wr1  = (const float*)d_in[3];
  const float* att1 = (const float*)d_in[4];
  const float* b1   = (const float*)d_in[5];
  const float* Wl2  = (const float*)d_in[6];
  const float* Wr2  = (const float*)d_in[7];
  const float* att2 = (const float*)d_in[8];
  const float* b2   = (const float*)d_in[9];
  const float* Wi1  = (const float*)d_in[10];
  const float* bi1  = (const float*)d_in[11];
  const float* Wi2  = (const float*)d_in[12];
  const float* bi2  = (const float*)d_in[13];
  float* out = (float*)d_out;

  char* ws = (char*)d_ws;
  size_t off = 0;
  auto alloc = [&](size_t bytes) {
    void* p = ws + off;
    off = (off + bytes + 255) & ~(size_t)255;
    return p;
  };
  unsigned short* xl    = (unsigned short*)alloc((size_t)NN * FD * 2);   // 12.8 MB
  unsigned short* xr    = (unsigned short*)alloc((size_t)NN * FD * 2);   // 12.8 MB
  unsigned short* Ahi   = (unsigned short*)alloc((size_t)NN * FD * 2);   // 12.8 MB
  unsigned short* Alo   = (unsigned short*)alloc((size_t)NN * FD * 2);   // 12.8 MB
  float*          h1    = (float*)alloc((size_t)NN * FD * 4);            // 25.6 MB
  float*          h2    = (float*)alloc((size_t)NN * FD * 4);            // 25.6 MB
  unsigned short* Bpack = (unsigned short*)alloc((size_t)2 * TT * 2 * 16384 * 2); // 0.5 MB
  int*            col   = (int*)alloc((size_t)TT * EE * 4);              // 6.4 MB
  int*            rowp  = (int*)alloc((size_t)TT * RPS * 4);             // 0.8 MB
  // aliases (CSR-phase only; dead before xl/xr/h2 are written)
  int* cnt  = (int*)xl;                      // TT*NN ints
  int* bcur = (int*)xr;                      // TT*NBKT ints
  int* psum = (int*)((char*)xr + 8192);      // 100 ints
  unsigned int* ebuf = (unsigned int*)h2;    // TT*NBKT*BCAP u32 = 12.85 MB

  // --- CSR build (shared by both layers) ---
  hipMemsetAsync(cnt, 0, (size_t)TT * NN * 4, stream);
  hipMemsetAsync(bcur, 0, (size_t)TT * NBKT * 4, stream);
  k_cvtW<<<1024, 256, 0, stream>>>(Wl1, Wr1, Wl2, Wr2, Bpack);
  k_hist2<<<(TT * EE + 255) / 256, 256, 0, stream>>>(ei, cnt);
  k_scan_p1<<<dim3(25, TT), 512, 0, stream>>>(cnt, rowp, psum);
  k_scan_p2<<<1, 128, 0, stream>>>(psum);
  k_scan_p3<<<dim3(25, TT), 512, 0, stream>>>(psum, rowp);
  k_bucket<<<dim3(98, TT), 256, 0, stream>>>(ei, bcur, ebuf);
  k_scatter2<<<dim3(NBKT, TT), 256, 0, stream>>>(ebuf, bcur, rowp, col);

  // --- layer 1 ---
  k_cvtA<<<6250, 256, 0, stream>>>(x, Ahi, Alo, 0);
  for (int t = 0; t < TT; ++t) {
    k_gemm<<<782, 128, 0, stream>>>(Ahi, Alo, Bpack + (size_t)((0 * TT + t) * 2) * 16384, xl, xr);
    k_agg<<<(NN + 3) / 4, 256, 0, stream>>>(xl, xr, col + (size_t)t * EE,
                                            rowp + (size_t)t * RPS,
                                            att1 + t * 128, b1 + t * 128, h1, t == 0);
  }
  // --- layer 2 ---
  k_cvtA<<<6250, 256, 0, stream>>>(h1, Ahi, Alo, 1);
  for (int t = 0; t < TT; ++t) {
    k_gemm<<<782, 128, 0, stream>>>(Ahi, Alo, Bpack + (size_t)((1 * TT + t) * 2) * 16384, xl, xr);
    k_agg<<<(NN + 3) / 4, 256, 0, stream>>>(xl, xr, col + (size_t)t * EE,
                                            rowp + (size_t)t * RPS,
                                            att2 + t * 128, b2 + t * 128, h2, t == 0);
  }
  // --- MLP head ---
  k_mlp<<<(NN + 255) / 256, 256, 0, stream>>>(h2, Wi1, bi1, Wi2, bi2, out);
}

// Round 4
// 654.213 us; speedup vs baseline: 2.1782x; 1.2176x over previous
//
#include <hip/hip_runtime.h>
#include <hip/hip_bf16.h>
#include <math.h>

#define NN 50000
#define EE 400000
#define TT 4
#define FD 128
#define RPS 50004        // rowp stride per type
#define NBKT 196         // buckets per type = ceil(NN/256)
#define BCAP 4096        // fixed capacity per bucket (mean fill ~2040, max ~2600)

typedef __attribute__((ext_vector_type(8))) short bf16x8;
typedef __attribute__((ext_vector_type(4))) float f32x4;

__device__ inline float bf2f(unsigned short u) {
  union { unsigned int i; float f; } x; x.i = ((unsigned int)u) << 16; return x.f;
}
__device__ inline unsigned short f2bf(float f) {
  __hip_bfloat16 h = __float2bfloat16(f);
  unsigned short u; __builtin_memcpy(&u, &h, 2); return u;
}
__device__ inline float gsum(float v) {   // sum within each 32-lane half-wave
  v += __shfl_xor(v, 1);
  v += __shfl_xor(v, 2);
  v += __shfl_xor(v, 4);
  v += __shfl_xor(v, 8);
  v += __shfl_xor(v, 16);
  return v;
}

// ---------- weight pack: W[k][c] f32 -> bf16 fragments in MFMA order ----------
// region R = ((layer*TT + t)*2 + lr), 16384 bf16 per region.
__global__ void k_cvtW(const float* __restrict__ Wl1, const float* __restrict__ Wr1,
                       const float* __restrict__ Wl2, const float* __restrict__ Wr2,
                       unsigned short* __restrict__ Bpack) {
  const int idx = blockIdx.x * 256 + threadIdx.x;      // 2*4*2*16384 = 262144
  const int R = idx >> 14;
  const int kc = idx & 16383;
  const int lr = R & 1, t = (R >> 1) & 3, layer = R >> 3;
  const float* W = layer ? (lr ? Wr2 : Wl2) : (lr ? Wr1 : Wl1);
  const float v = W[t * 16384 + kc];
  const int k = kc >> 7, c = kc & 127;
  const int nt = c >> 4, ks = k >> 5, g = (k >> 3) & 3, j = k & 7;
  const int lane = g * 16 + (c & 15);
  Bpack[(size_t)R * 16384 + ((nt * 4 + ks) * 64 + lane) * 8 + j] = f2bf(v);
}

// ---------- A split: f32 -> (hi, lo) bf16 ----------
__global__ void k_cvtA(const float* __restrict__ src, unsigned short* __restrict__ ahi,
                       unsigned short* __restrict__ alo) {
  const int idx = blockIdx.x * 256 + threadIdx.x;      // NN*FD/4 = 1,600,000
  float4 v = ((const float4*)src)[idx];
  const unsigned short h0 = f2bf(v.x), h1 = f2bf(v.y), h2 = f2bf(v.z), h3 = f2bf(v.w);
  const unsigned short l0 = f2bf(v.x - bf2f(h0)), l1 = f2bf(v.y - bf2f(h1));
  const unsigned short l2 = f2bf(v.z - bf2f(h2)), l3 = f2bf(v.w - bf2f(h3));
  uint2 hv, lv;
  hv.x = (unsigned)h0 | ((unsigned)h1 << 16); hv.y = (unsigned)h2 | ((unsigned)h3 << 16);
  lv.x = (unsigned)l0 | ((unsigned)l1 << 16); lv.y = (unsigned)l2 | ((unsigned)l3 << 16);
  ((uint2*)ahi)[idx] = hv;
  ((uint2*)alo)[idx] = lv;
}

// ---------- MFMA GEMM, all 4 types in one dispatch: grid (782, TT) ----------
// block = 128 thr (2 waves), wave owns 32 rows x 256 cols; no LDS.
__global__ __launch_bounds__(128) void k_gemm4(
    const unsigned short* __restrict__ Ahi, const unsigned short* __restrict__ Alo,
    const unsigned short* __restrict__ Bbase,
    unsigned short* __restrict__ xl4, unsigned short* __restrict__ xr4) {
  const int t = blockIdx.y;
  const unsigned short* Bpt = Bbase + (size_t)t * 2 * 16384;
  unsigned short* xl = xl4 + (size_t)t * NN * FD;
  unsigned short* xr = xr4 + (size_t)t * NN * FD;
  const int tid = threadIdx.x;
  const int lane = tid & 63;
  const int w = tid >> 6;
  const int rh = lane & 15, g = lane >> 4;
  const int m0 = blockIdx.x * 64 + w * 32;
  f32x4 acc[2][16];
  #pragma unroll
  for (int a = 0; a < 2; ++a)
    #pragma unroll
    for (int b = 0; b < 16; ++b) acc[a][b] = (f32x4){0.f, 0.f, 0.f, 0.f};
  int r0 = m0 + rh;      if (r0 > NN - 1) r0 = NN - 1;
  int r1 = m0 + 16 + rh; if (r1 > NN - 1) r1 = NN - 1;
  #pragma unroll
  for (int ks = 0; ks < 4; ++ks) {
    const int ko = ks * 32 + g * 8;
    const bf16x8 ah0 = *(const bf16x8*)(Ahi + (size_t)r0 * FD + ko);
    const bf16x8 al0 = *(const bf16x8*)(Alo + (size_t)r0 * FD + ko);
    const bf16x8 ah1 = *(const bf16x8*)(Ahi + (size_t)r1 * FD + ko);
    const bf16x8 al1 = *(const bf16x8*)(Alo + (size_t)r1 * FD + ko);
    #pragma unroll
    for (int nt = 0; nt < 16; ++nt) {
      const bf16x8 b = *(const bf16x8*)(Bpt + (nt >> 3) * 16384 +
                                        (((nt & 7) * 4 + ks) * 64 + lane) * 8);
      acc[0][nt] = __builtin_amdgcn_mfma_f32_16x16x32_bf16(ah0, b, acc[0][nt], 0, 0, 0);
      acc[0][nt] = __builtin_amdgcn_mfma_f32_16x16x32_bf16(al0, b, acc[0][nt], 0, 0, 0);
      acc[1][nt] = __builtin_amdgcn_mfma_f32_16x16x32_bf16(ah1, b, acc[1][nt], 0, 0, 0);
      acc[1][nt] = __builtin_amdgcn_mfma_f32_16x16x32_bf16(al1, b, acc[1][nt], 0, 0, 0);
    }
  }
  #pragma unroll
  for (int mt = 0; mt < 2; ++mt)
    #pragma unroll
    for (int nt = 0; nt < 16; ++nt) {
      unsigned short* op = (nt < 8) ? xl : xr;
      const int cb = (nt & 7) * 16 + rh;
      #pragma unroll
      for (int r = 0; r < 4; ++r) {
        const int row = m0 + mt * 16 + g * 4 + r;   // m89-verified C/D mapping
        if (row < NN) op[(size_t)row * FD + cb] = f2bf(acc[mt][nt][r]);
      }
    }
}

// ---------- CSR build: bucket -> bucket-scan -> scatter(+rowp derivation) ----
__global__ __launch_bounds__(256) void k_bucket(const int* __restrict__ ei,
                                                int* __restrict__ bcur,
                                                unsigned int* __restrict__ ebuf) {
  __shared__ int lcnt[NBKT], lbase[NBKT];
  const int t = blockIdx.y, tid = threadIdx.x;
  const int cbase = blockIdx.x * 4096;
  if (tid < NBKT) lcnt[tid] = 0;
  __syncthreads();
  const int* srcp = ei + (size_t)t * 2 * EE;
  const int* dstp = srcp + EE;
  unsigned int pk[16]; int rk[16];
  #pragma unroll
  for (int i = 0; i < 16; ++i) {
    const int e = cbase + i * 256 + tid;
    rk[i] = -1;
    if (e < EE) {
      const int s = srcp[e], dd = dstp[e];
      const int b = dd >> 8;
      pk[i] = ((unsigned)dd << 16) | (unsigned)s;
      rk[i] = (atomicAdd(&lcnt[b], 1) << 8) | b;
    }
  }
  __syncthreads();
  if (tid < NBKT && lcnt[tid] > 0) lbase[tid] = atomicAdd(&bcur[t * NBKT + tid], lcnt[tid]);
  __syncthreads();
  #pragma unroll
  for (int i = 0; i < 16; ++i) {
    if (rk[i] >= 0) {
      const int b = rk[i] & 255, r = rk[i] >> 8;
      ebuf[((size_t)t * NBKT + b) * BCAP + lbase[b] + r] = pk[i];
    }
  }
}

// scan of per-bucket totals (4 x 196, segmented by type) -> bucket base offsets
__global__ void k_bktscan(const int* __restrict__ bcur, int* __restrict__ bbase) {
  __shared__ int s[TT * NBKT];
  const int tid = threadIdx.x;   // 1024
  int v0 = 0;
  if (tid < TT * NBKT) { v0 = bcur[tid]; s[tid] = v0; }
  __syncthreads();
  #pragma unroll
  for (int off = 1; off < NBKT; off <<= 1) {
    int a = 0;
    if (tid < TT * NBKT && (tid % NBKT) >= off) a = s[tid - off];
    __syncthreads();
    if (tid < TT * NBKT) s[tid] += a;
    __syncthreads();
  }
  if (tid < TT * NBKT) bbase[tid] = s[tid] - v0;   // exclusive within type
}

// one block per (bucket, type): derive rowp for its 256 dsts, then scatter.
__global__ __launch_bounds__(256) void k_scatter3(const unsigned int* __restrict__ ebuf,
                                                  const int* __restrict__ bcur,
                                                  const int* __restrict__ bbase,
                                                  int* __restrict__ rowp,
                                                  int* __restrict__ col) {
  __shared__ int lc[256], sc[256];
  const int b = blockIdx.x, t = blockIdx.y, tid = threadIdx.x;
  const int d0 = b << 8;
  const int nd = (NN - d0 < 256) ? (NN - d0) : 256;
  const int cnt = bcur[t * NBKT + b];
  const int base = bbase[t * NBKT + b];
  const unsigned int* eb = ebuf + ((size_t)t * NBKT + b) * BCAP;
  lc[tid] = 0;
  __syncthreads();
  for (int j = tid; j < cnt; j += 256) {
    atomicAdd(&lc[(eb[j] >> 16) - d0], 1);
  }
  __syncthreads();
  const int v = lc[tid];
  sc[tid] = v;
  __syncthreads();
  #pragma unroll
  for (int off = 1; off < 256; off <<= 1) {
    const int a = (tid >= off) ? sc[tid - off] : 0;
    __syncthreads();
    sc[tid] += a;
    __syncthreads();
  }
  const int excl = base + sc[tid] - v;
  if (tid < nd) rowp[(size_t)t * RPS + d0 + tid] = excl;
  if (b == NBKT - 1 && tid == 0) rowp[(size_t)t * RPS + NN] = EE;
  lc[tid] = excl;          // becomes the scatter cursor
  __syncthreads();
  for (int j = tid; j < cnt; j += 256) {
    const unsigned int u = eb[j];
    const int pos = atomicAdd(&lc[(u >> 16) - d0], 1);
    col[(size_t)t * EE + pos] = (int)(u & 0xFFFF);
  }
}

// ---------- GATv2 aggregation, all 4 types per block (wave t = type t) -------
// lane owns flat channels {2*lane, 2*lane+1}; lanes 0-31 = head0, 32-63 = head1.
// mode 0: epilogue = relu + bf16 hi/lo split into ahi/alo (layer-1 -> layer-2)
// mode 1: epilogue = f32 write to hout (layer-2 -> MLP)
__global__ __launch_bounds__(256) void k_agg4(
    const unsigned short* __restrict__ xl4, const unsigned short* __restrict__ xr4,
    const int* __restrict__ col, const int* __restrict__ rowp,
    const float* __restrict__ att, const float* __restrict__ bias,
    float* __restrict__ hout, unsigned short* __restrict__ ahi,
    unsigned short* __restrict__ alo, const int mode) {
  __shared__ float sh0[256], sh1[256];
  const int tid = threadIdx.x;
  const int lane = tid & 63, t = tid >> 6;
  const int d = blockIdx.x;
  const unsigned short* xl = xl4 + (size_t)t * NN * FD;
  const unsigned short* xr = xr4 + (size_t)t * NN * FD;
  const int* colt = col + (size_t)t * EE;
  const float2 av = ((const float2*)(att + t * FD))[lane];
  unsigned int ur, ulp;
  __builtin_memcpy(&ur, xr + (size_t)d * FD + 2 * lane, 4);
  __builtin_memcpy(&ulp, xl + (size_t)d * FD + 2 * lane, 4);
  const float xr0 = bf2f((unsigned short)(ur & 0xFFFF)), xr1 = bf2f((unsigned short)(ur >> 16));
  const float sl0 = bf2f((unsigned short)(ulp & 0xFFFF)), sl1 = bf2f((unsigned short)(ulp >> 16));
  float v0 = sl0 + xr0; v0 = v0 > 0.f ? v0 : 0.2f * v0;
  float v1 = sl1 + xr1; v1 = v1 > 0.f ? v1 : 0.2f * v1;
  float m = gsum(av.x * v0 + av.y * v1);     // self-loop score
  float den = 1.f, ac0 = sl0, ac1 = sl1;
  int e = rowp[(size_t)t * RPS + d];
  const int end = rowp[(size_t)t * RPS + d + 1];
  for (; e + 1 < end; e += 2) {
    const int s0 = colt[e], s1 = colt[e + 1];
    unsigned int u0, u1;
    __builtin_memcpy(&u0, xl + (size_t)s0 * FD + 2 * lane, 4);
    __builtin_memcpy(&u1, xl + (size_t)s1 * FD + 2 * lane, 4);
    const float x00 = bf2f((unsigned short)(u0 & 0xFFFF)), x01 = bf2f((unsigned short)(u0 >> 16));
    const float x10 = bf2f((unsigned short)(u1 & 0xFFFF)), x11 = bf2f((unsigned short)(u1 >> 16));
    float a0 = x00 + xr0; a0 = a0 > 0.f ? a0 : 0.2f * a0;
    float a1 = x01 + xr1; a1 = a1 > 0.f ? a1 : 0.2f * a1;
    float b0 = x10 + xr0; b0 = b0 > 0.f ? b0 : 0.2f * b0;
    float b1 = x11 + xr1; b1 = b1 > 0.f ? b1 : 0.2f * b1;
    const float q0 = gsum(av.x * a0 + av.y * a1);
    const float q1 = gsum(av.x * b0 + av.y * b1);
    const float nm = fmaxf(m, fmaxf(q0, q1));
    const float sc = __expf(m - nm), w0 = __expf(q0 - nm), w1 = __expf(q1 - nm);
    den = den * sc + w0 + w1;
    ac0 = ac0 * sc + w0 * x00 + w1 * x10;
    ac1 = ac1 * sc + w0 * x01 + w1 * x11;
    m = nm;
  }
  if (e < end) {
    const int s0 = colt[e];
    unsigned int u0;
    __builtin_memcpy(&u0, xl + (size_t)s0 * FD + 2 * lane, 4);
    const float x00 = bf2f((unsigned short)(u0 & 0xFFFF)), x01 = bf2f((unsigned short)(u0 >> 16));
    float a0 = x00 + xr0; a0 = a0 > 0.f ? a0 : 0.2f * a0;
    float a1 = x01 + xr1; a1 = a1 > 0.f ? a1 : 0.2f * a1;
    const float q0 = gsum(av.x * a0 + av.y * a1);
    const float nm = fmaxf(m, q0);
    const float sc = __expf(m - nm), w0 = __expf(q0 - nm);
    den = den * sc + w0;
    ac0 = ac0 * sc + w0 * x00;
    ac1 = ac1 * sc + w0 * x01;
  }
  const float2 bv = ((const float2*)(bias + t * FD))[lane];
  sh0[tid] = ac0 / den + bv.x;
  sh1[tid] = ac1 / den + bv.y;
  __syncthreads();
  if (tid < 64) {
    float s0 = sh0[tid] + sh0[64 + tid] + sh0[128 + tid] + sh0[192 + tid];
    float s1 = sh1[tid] + sh1[64 + tid] + sh1[128 + tid] + sh1[192 + tid];
    if (mode == 0) {
      s0 = fmaxf(s0, 0.f); s1 = fmaxf(s1, 0.f);
      const unsigned short h0 = f2bf(s0), h1 = f2bf(s1);
      const unsigned short l0 = f2bf(s0 - bf2f(h0)), l1 = f2bf(s1 - bf2f(h1));
      ((unsigned int*)ahi)[(size_t)d * 64 + tid] = (unsigned)h0 | ((unsigned)h1 << 16);
      ((unsigned int*)alo)[(size_t)d * 64 + tid] = (unsigned)l0 | ((unsigned)l1 << 16);
    } else {
      ((float2*)(hout + (size_t)d * FD))[tid] = make_float2(s0, s1);
    }
  }
}

// ---------- MLP head (relu on h fused) ----------
__global__ __launch_bounds__(256) void k_mlp(const float* __restrict__ h,
                                             const float* __restrict__ W1,
                                             const float* __restrict__ b1,
                                             const float* __restrict__ W2,
                                             const float* __restrict__ b2,
                                             float* __restrict__ out) {
  __shared__ float sW1[128 * 8];
  __shared__ float sW2[8 * 10];
  __shared__ float sb1[8], sb2[10];
  for (int i = threadIdx.x; i < 1024; i += 256) sW1[i] = W1[i];
  if (threadIdx.x < 80) sW2[threadIdx.x] = W2[threadIdx.x];
  if (threadIdx.x < 8)  sb1[threadIdx.x] = b1[threadIdx.x];
  if (threadIdx.x < 10) sb2[threadIdx.x] = b2[threadIdx.x];
  __syncthreads();
  const int n = blockIdx.x * 256 + threadIdx.x;
  if (n >= NN) return;
  const float* hn = h + (size_t)n * FD;
  float z[8];
  #pragma unroll
  for (int j = 0; j < 8; ++j) z[j] = sb1[j];
  for (int k = 0; k < FD; k += 4) {
    float4 hv = *(const float4*)(hn + k);
    hv.x = fmaxf(hv.x, 0.f); hv.y = fmaxf(hv.y, 0.f);
    hv.z = fmaxf(hv.z, 0.f); hv.w = fmaxf(hv.w, 0.f);
    #pragma unroll
    for (int j = 0; j < 8; ++j) {
      z[j] += hv.x * sW1[(k + 0) * 8 + j] + hv.y * sW1[(k + 1) * 8 + j]
            + hv.z * sW1[(k + 2) * 8 + j] + hv.w * sW1[(k + 3) * 8 + j];
    }
  }
  #pragma unroll
  for (int j = 0; j < 8; ++j) z[j] = fmaxf(z[j], 0.f);
  float o[10];
  #pragma unroll
  for (int c = 0; c < 10; ++c) o[c] = sb2[c];
  #pragma unroll
  for (int j = 0; j < 8; ++j)
    #pragma unroll
    for (int c = 0; c < 10; ++c) o[c] += z[j] * sW2[j * 10 + c];
  float* op = out + (size_t)n * 10;
  #pragma unroll
  for (int c = 0; c < 10; ++c) op[c] = o[c];
}

extern "C" void kernel_launch(void* const* d_in, const int* in_sizes, int n_in,
                              void* d_out, int out_size, void* d_ws, size_t ws_size,
                              hipStream_t stream) {
  const float* x    = (const float*)d_in[0];
  const int*   ei   = (const int*)d_in[1];
  const float* Wl1  = (const float*)d_in[2];
  const float* Wr1  = (const float*)d_in[3];
  const float* att1 = (const float*)d_in[4];
  const float* b1   = (const float*)d_in[5];
  const float* Wl2  = (const float*)d_in[6];
  const float* Wr2  = (const float*)d_in[7];
  const float* att2 = (const float*)d_in[8];
  const float* b2   = (const float*)d_in[9];
  const float* Wi1  = (const float*)d_in[10];
  const float* bi1  = (const float*)d_in[11];
  const float* Wi2  = (const float*)d_in[12];
  const float* bi2  = (const float*)d_in[13];
  float* out = (float*)d_out;

  char* ws = (char*)d_ws;
  size_t off = 0;
  auto alloc = [&](size_t bytes) {
    void* p = ws + off;
    off = (off + bytes + 255) & ~(size_t)255;
    return p;
  };
  unsigned short* xl4   = (unsigned short*)alloc((size_t)TT * NN * FD * 2); // 51.2 MB
  unsigned short* xr4   = (unsigned short*)alloc((size_t)TT * NN * FD * 2); // 51.2 MB
  unsigned short* Ahi   = (unsigned short*)alloc((size_t)NN * FD * 2);      // 12.8 MB
  unsigned short* Alo   = (unsigned short*)alloc((size_t)NN * FD * 2);      // 12.8 MB
  float*          h2    = (float*)alloc((size_t)NN * FD * 4);               // 25.6 MB
  unsigned short* Bpack = (unsigned short*)alloc((size_t)2 * TT * 2 * 16384 * 2); // 0.5 MB
  int*            col   = (int*)alloc((size_t)TT * EE * 4);                 // 6.4 MB
  int*            rowp  = (int*)alloc((size_t)TT * RPS * 4);                // 0.8 MB
  int*            bcur  = (int*)alloc((size_t)TT * NBKT * 4);
  int*            bbase = (int*)alloc((size_t)TT * NBKT * 4);
  // alias: ebuf (12.85 MB, CSR phase only) on h2 (written only by layer-2 agg)
  unsigned int* ebuf = (unsigned int*)h2;

  // --- CSR build (shared by both layers) ---
  hipMemsetAsync(bcur, 0, (size_t)TT * NBKT * 4, stream);
  k_cvtW<<<1024, 256, 0, stream>>>(Wl1, Wr1, Wl2, Wr2, Bpack);
  k_bucket<<<dim3(98, TT), 256, 0, stream>>>(ei, bcur, ebuf);
  k_bktscan<<<1, 1024, 0, stream>>>(bcur, bbase);
  k_scatter3<<<dim3(NBKT, TT), 256, 0, stream>>>(ebuf, bcur, bbase, rowp, col);

  // --- layer 1 ---
  k_cvtA<<<6250, 256, 0, stream>>>(x, Ahi, Alo);
  k_gemm4<<<dim3(782, TT), 128, 0, stream>>>(Ahi, Alo, Bpack, xl4, xr4);
  k_agg4<<<NN, 256, 0, stream>>>(xl4, xr4, col, rowp, att1, b1,
                                 nullptr, Ahi, Alo, 0);
  // --- layer 2 ---
  k_gemm4<<<dim3(782, TT), 128, 0, stream>>>(Ahi, Alo, Bpack + (size_t)TT * 2 * 16384,
                                             xl4, xr4);
  k_agg4<<<NN, 256, 0, stream>>>(xl4, xr4, col, rowp, att2, b2,
                                 h2, nullptr, nullptr, 1);
  // --- MLP head ---
  k_mlp<<<(NN + 255) / 256, 256, 0, stream>>>(h2, Wi1, bi1, Wi2, bi2, out);
}

// Round 5
// 564.693 us; speedup vs baseline: 2.5235x; 1.1585x over previous
//
#include <hip/hip_runtime.h>
#include <hip/hip_bf16.h>
#include <math.h>

#define NN 50000
#define EE 400000
#define TT 4
#define FD 128
#define RPS 50004        // rowp stride per type
#define NBKT 196         // buckets per type = ceil(NN/256)
#define BCAP 4096        // fixed capacity per bucket (mean fill ~2040, max ~2600)
#define LOG2E 1.44269504f

typedef __attribute__((ext_vector_type(8))) short bf16x8;
typedef __attribute__((ext_vector_type(4))) float f32x4;

__device__ inline float bf2f(unsigned short u) {
  union { unsigned int i; float f; } x; x.i = ((unsigned int)u) << 16; return x.f;
}
__device__ inline unsigned short f2bf(float f) {
  __hip_bfloat16 h = __float2bfloat16(f);
  unsigned short u; __builtin_memcpy(&u, &h, 2); return u;
}
__device__ inline float blo(unsigned int u) {
  union { unsigned int i; float f; } x; x.i = u << 16; return x.f;
}
__device__ inline float bhi(unsigned int u) {
  union { unsigned int i; float f; } x; x.i = u & 0xFFFF0000u; return x.f;
}
__device__ inline float fexp2(float x) { return __builtin_amdgcn_exp2f(x); }

__device__ inline float dppadd(float v, int ctrl) {
  int s = __builtin_bit_cast(int, v);
  // compiler fuses mov_dpp+add into v_add_f32_dpp; stays on the VALU pipe
  return v;
}
// sum within each 32-lane half (lanes 0-31 | 32-63 independent):
// xor1, xor2 via quad_perm; xor4/xor8 replaced by half/full row mirrors
// (valid for sums: values are uniform within each already-reduced group);
// final xor16 via one ds_swizzle.
__device__ inline float qsum32(float v) {
  v += __builtin_bit_cast(float, __builtin_amdgcn_update_dpp(
         0, __builtin_bit_cast(int, v), 0xB1, 0xF, 0xF, true));   // quad_perm [1,0,3,2]
  v += __builtin_bit_cast(float, __builtin_amdgcn_update_dpp(
         0, __builtin_bit_cast(int, v), 0x4E, 0xF, 0xF, true));   // quad_perm [2,3,0,1]
  v += __builtin_bit_cast(float, __builtin_amdgcn_update_dpp(
         0, __builtin_bit_cast(int, v), 0x141, 0xF, 0xF, true));  // row_half_mirror
  v += __builtin_bit_cast(float, __builtin_amdgcn_update_dpp(
         0, __builtin_bit_cast(int, v), 0x140, 0xF, 0xF, true));  // row_mirror
  v += __builtin_bit_cast(float, __builtin_amdgcn_ds_swizzle(
         __builtin_bit_cast(int, v), 0x401F));                    // xor 16
  return v;
}

// ---------- weight pack: W[k][c] f32 -> bf16 fragments in MFMA order ----------
__global__ void k_cvtW(const float* __restrict__ Wl1, const float* __restrict__ Wr1,
                       const float* __restrict__ Wl2, const float* __restrict__ Wr2,
                       unsigned short* __restrict__ Bpack) {
  const int idx = blockIdx.x * 256 + threadIdx.x;      // 2*4*2*16384 = 262144
  const int R = idx >> 14;
  const int kc = idx & 16383;
  const int lr = R & 1, t = (R >> 1) & 3, layer = R >> 3;
  const float* W = layer ? (lr ? Wr2 : Wl2) : (lr ? Wr1 : Wl1);
  const float v = W[t * 16384 + kc];
  const int k = kc >> 7, c = kc & 127;
  const int nt = c >> 4, ks = k >> 5, g = (k >> 3) & 3, j = k & 7;
  const int lane = g * 16 + (c & 15);
  Bpack[(size_t)R * 16384 + ((nt * 4 + ks) * 64 + lane) * 8 + j] = f2bf(v);
}

// ---------- A split: f32 -> (hi, lo) bf16 ----------
__global__ void k_cvtA(const float* __restrict__ src, unsigned short* __restrict__ ahi,
                       unsigned short* __restrict__ alo) {
  const int idx = blockIdx.x * 256 + threadIdx.x;      // NN*FD/4 = 1,600,000
  float4 v = ((const float4*)src)[idx];
  const unsigned short h0 = f2bf(v.x), h1 = f2bf(v.y), h2 = f2bf(v.z), h3 = f2bf(v.w);
  const unsigned short l0 = f2bf(v.x - bf2f(h0)), l1 = f2bf(v.y - bf2f(h1));
  const unsigned short l2 = f2bf(v.z - bf2f(h2)), l3 = f2bf(v.w - bf2f(h3));
  uint2 hv, lv;
  hv.x = (unsigned)h0 | ((unsigned)h1 << 16); hv.y = (unsigned)h2 | ((unsigned)h3 << 16);
  lv.x = (unsigned)l0 | ((unsigned)l1 << 16); lv.y = (unsigned)l2 | ((unsigned)l3 << 16);
  ((uint2*)ahi)[idx] = hv;
  ((uint2*)alo)[idx] = lv;
}

// ---------- MFMA GEMM, all 4 types in one dispatch: grid (782, TT) ----------
__global__ __launch_bounds__(128) void k_gemm4(
    const unsigned short* __restrict__ Ahi, const unsigned short* __restrict__ Alo,
    const unsigned short* __restrict__ Bbase,
    unsigned short* __restrict__ xl4, unsigned short* __restrict__ xr4) {
  const int t = blockIdx.y;
  const unsigned short* Bpt = Bbase + (size_t)t * 2 * 16384;
  unsigned short* xl = xl4 + (size_t)t * NN * FD;
  unsigned short* xr = xr4 + (size_t)t * NN * FD;
  const int tid = threadIdx.x;
  const int lane = tid & 63;
  const int w = tid >> 6;
  const int rh = lane & 15, g = lane >> 4;
  const int m0 = blockIdx.x * 64 + w * 32;
  f32x4 acc[2][16];
  #pragma unroll
  for (int a = 0; a < 2; ++a)
    #pragma unroll
    for (int b = 0; b < 16; ++b) acc[a][b] = (f32x4){0.f, 0.f, 0.f, 0.f};
  int r0 = m0 + rh;      if (r0 > NN - 1) r0 = NN - 1;
  int r1 = m0 + 16 + rh; if (r1 > NN - 1) r1 = NN - 1;
  #pragma unroll
  for (int ks = 0; ks < 4; ++ks) {
    const int ko = ks * 32 + g * 8;
    const bf16x8 ah0 = *(const bf16x8*)(Ahi + (size_t)r0 * FD + ko);
    const bf16x8 al0 = *(const bf16x8*)(Alo + (size_t)r0 * FD + ko);
    const bf16x8 ah1 = *(const bf16x8*)(Ahi + (size_t)r1 * FD + ko);
    const bf16x8 al1 = *(const bf16x8*)(Alo + (size_t)r1 * FD + ko);
    #pragma unroll
    for (int nt = 0; nt < 16; ++nt) {
      const bf16x8 b = *(const bf16x8*)(Bpt + (nt >> 3) * 16384 +
                                        (((nt & 7) * 4 + ks) * 64 + lane) * 8);
      acc[0][nt] = __builtin_amdgcn_mfma_f32_16x16x32_bf16(ah0, b, acc[0][nt], 0, 0, 0);
      acc[0][nt] = __builtin_amdgcn_mfma_f32_16x16x32_bf16(al0, b, acc[0][nt], 0, 0, 0);
      acc[1][nt] = __builtin_amdgcn_mfma_f32_16x16x32_bf16(ah1, b, acc[1][nt], 0, 0, 0);
      acc[1][nt] = __builtin_amdgcn_mfma_f32_16x16x32_bf16(al1, b, acc[1][nt], 0, 0, 0);
    }
  }
  #pragma unroll
  for (int mt = 0; mt < 2; ++mt)
    #pragma unroll
    for (int nt = 0; nt < 16; ++nt) {
      unsigned short* op = (nt < 8) ? xl : xr;
      const int cb = (nt & 7) * 16 + rh;
      #pragma unroll
      for (int r = 0; r < 4; ++r) {
        const int row = m0 + mt * 16 + g * 4 + r;   // m89-verified C/D mapping
        if (row < NN) op[(size_t)row * FD + cb] = f2bf(acc[mt][nt][r]);
      }
    }
}

// ---------- CSR build: bucket -> bucket-scan -> scatter(+rowp derivation) ----
__global__ __launch_bounds__(256) void k_bucket(const int* __restrict__ ei,
                                                int* __restrict__ bcur,
                                                unsigned int* __restrict__ ebuf) {
  __shared__ int lcnt[NBKT], lbase[NBKT];
  const int t = blockIdx.y, tid = threadIdx.x;
  const int cbase = blockIdx.x * 4096;
  if (tid < NBKT) lcnt[tid] = 0;
  __syncthreads();
  const int* srcp = ei + (size_t)t * 2 * EE;
  const int* dstp = srcp + EE;
  unsigned int pk[16]; int rk[16];
  #pragma unroll
  for (int i = 0; i < 16; ++i) {
    const int e = cbase + i * 256 + tid;
    rk[i] = -1;
    if (e < EE) {
      const int s = srcp[e], dd = dstp[e];
      const int b = dd >> 8;
      pk[i] = ((unsigned)dd << 16) | (unsigned)s;
      rk[i] = (atomicAdd(&lcnt[b], 1) << 8) | b;
    }
  }
  __syncthreads();
  if (tid < NBKT && lcnt[tid] > 0) lbase[tid] = atomicAdd(&bcur[t * NBKT + tid], lcnt[tid]);
  __syncthreads();
  #pragma unroll
  for (int i = 0; i < 16; ++i) {
    if (rk[i] >= 0) {
      const int b = rk[i] & 255, r = rk[i] >> 8;
      ebuf[((size_t)t * NBKT + b) * BCAP + lbase[b] + r] = pk[i];
    }
  }
}

__global__ void k_bktscan(const int* __restrict__ bcur, int* __restrict__ bbase) {
  __shared__ int s[TT * NBKT];
  const int tid = threadIdx.x;   // 1024
  int v0 = 0;
  if (tid < TT * NBKT) { v0 = bcur[tid]; s[tid] = v0; }
  __syncthreads();
  #pragma unroll
  for (int off = 1; off < NBKT; off <<= 1) {
    int a = 0;
    if (tid < TT * NBKT && (tid % NBKT) >= off) a = s[tid - off];
    __syncthreads();
    if (tid < TT * NBKT) s[tid] += a;
    __syncthreads();
  }
  if (tid < TT * NBKT) bbase[tid] = s[tid] - v0;   // exclusive within type
}

__global__ __launch_bounds__(256) void k_scatter3(const unsigned int* __restrict__ ebuf,
                                                  const int* __restrict__ bcur,
                                                  const int* __restrict__ bbase,
                                                  int* __restrict__ rowp,
                                                  int* __restrict__ col) {
  __shared__ int lc[256], sc[256];
  const int b = blockIdx.x, t = blockIdx.y, tid = threadIdx.x;
  const int d0 = b << 8;
  const int nd = (NN - d0 < 256) ? (NN - d0) : 256;
  const int cnt = bcur[t * NBKT + b];
  const int base = bbase[t * NBKT + b];
  const unsigned int* eb = ebuf + ((size_t)t * NBKT + b) * BCAP;
  lc[tid] = 0;
  __syncthreads();
  for (int j = tid; j < cnt; j += 256) {
    atomicAdd(&lc[(eb[j] >> 16) - d0], 1);
  }
  __syncthreads();
  const int v = lc[tid];
  sc[tid] = v;
  __syncthreads();
  #pragma unroll
  for (int off = 1; off < 256; off <<= 1) {
    const int a = (tid >= off) ? sc[tid - off] : 0;
    __syncthreads();
    sc[tid] += a;
    __syncthreads();
  }
  const int excl = base + sc[tid] - v;
  if (tid < nd) rowp[(size_t)t * RPS + d0 + tid] = excl;
  if (b == NBKT - 1 && tid == 0) rowp[(size_t)t * RPS + NN] = EE;
  lc[tid] = excl;          // becomes the scatter cursor
  __syncthreads();
  for (int j = tid; j < cnt; j += 256) {
    const unsigned int u = eb[j];
    const int pos = atomicAdd(&lc[(u >> 16) - d0], 1);
    col[(size_t)t * EE + pos] = (int)(u & 0xFFFF);
  }
}

// ---------- GATv2 aggregation, all 4 types per block (wave t = type t) -------
// lane owns flat channels {2*lane, 2*lane+1}; lanes 0-31 = head0, 32-63 = head1.
// Scores in exp2 domain (att pre-scaled by log2(e)).
// mode 0: epilogue = relu + bf16 hi/lo split into ahi/alo (layer-1 -> layer-2)
// mode 1: epilogue = fused MLP head, writes final logits to out
__global__ __launch_bounds__(256) void k_agg4(
    const unsigned short* __restrict__ xl4, const unsigned short* __restrict__ xr4,
    const int* __restrict__ col, const int* __restrict__ rowp,
    const float* __restrict__ att, const float* __restrict__ bias,
    unsigned short* __restrict__ ahi, unsigned short* __restrict__ alo,
    const float* __restrict__ W1, const float* __restrict__ b1v,
    const float* __restrict__ W2, const float* __restrict__ b2v,
    float* __restrict__ out, const int mode) {
  __shared__ float sh0[256], sh1[256];
  const int tid = threadIdx.x;
  const int lane = tid & 63, t = tid >> 6;
  const int d = blockIdx.x;
  const unsigned short* xl = xl4 + (size_t)t * NN * FD;
  const unsigned short* xr = xr4 + (size_t)t * NN * FD;
  const int* colt = col + (size_t)t * EE;
  float2 av = ((const float2*)(att + t * FD))[lane];
  av.x *= LOG2E; av.y *= LOG2E;       // exp2 domain
  unsigned int ur, ulp;
  __builtin_memcpy(&ur, xr + (size_t)d * FD + 2 * lane, 4);
  __builtin_memcpy(&ulp, xl + (size_t)d * FD + 2 * lane, 4);
  const float xr0 = blo(ur), xr1 = bhi(ur);
  const float sl0 = blo(ulp), sl1 = bhi(ulp);
  // self-loop
  float v0 = sl0 + xr0; v0 = fmaxf(v0, 0.2f * v0);
  float v1 = sl1 + xr1; v1 = fmaxf(v1, 0.2f * v1);
  float m = qsum32(fmaf(av.y, v1, av.x * v0));
  float den = 1.f, ac0 = sl0, ac1 = sl1;
  int e = rowp[(size_t)t * RPS + d];
  const int end = rowp[(size_t)t * RPS + d + 1];
  for (; e + 3 < end; e += 4) {
    const int s0 = colt[e], s1 = colt[e + 1], s2 = colt[e + 2], s3 = colt[e + 3];
    unsigned int u0, u1, u2, u3;
    __builtin_memcpy(&u0, xl + (size_t)s0 * FD + 2 * lane, 4);
    __builtin_memcpy(&u1, xl + (size_t)s1 * FD + 2 * lane, 4);
    __builtin_memcpy(&u2, xl + (size_t)s2 * FD + 2 * lane, 4);
    __builtin_memcpy(&u3, xl + (size_t)s3 * FD + 2 * lane, 4);
    const float x00 = blo(u0), x01 = bhi(u0);
    const float x10 = blo(u1), x11 = bhi(u1);
    const float x20 = blo(u2), x21 = bhi(u2);
    const float x30 = blo(u3), x31 = bhi(u3);
    float a0 = x00 + xr0, a1 = x01 + xr1;
    float b0 = x10 + xr0, b1 = x11 + xr1;
    float c0 = x20 + xr0, c1 = x21 + xr1;
    float d0 = x30 + xr0, d1 = x31 + xr1;
    a0 = fmaxf(a0, 0.2f * a0); a1 = fmaxf(a1, 0.2f * a1);
    b0 = fmaxf(b0, 0.2f * b0); b1 = fmaxf(b1, 0.2f * b1);
    c0 = fmaxf(c0, 0.2f * c0); c1 = fmaxf(c1, 0.2f * c1);
    d0 = fmaxf(d0, 0.2f * d0); d1 = fmaxf(d1, 0.2f * d1);
    float p0 = qsum32(fmaf(av.y, a1, av.x * a0));
    float p1 = qsum32(fmaf(av.y, b1, av.x * b0));
    float p2 = qsum32(fmaf(av.y, c1, av.x * c0));
    float p3 = qsum32(fmaf(av.y, d1, av.x * d0));
    const float nm = fmaxf(fmaxf(fmaxf(p0, p1), fmaxf(p2, p3)), m);
    const float scl = fexp2(m - nm);
    const float w0 = fexp2(p0 - nm), w1 = fexp2(p1 - nm);
    const float w2 = fexp2(p2 - nm), w3 = fexp2(p3 - nm);
    den = fmaf(den, scl, (w0 + w1) + (w2 + w3));
    ac0 = fmaf(ac0, scl, fmaf(w0, x00, fmaf(w1, x10, fmaf(w2, x20, w3 * x30))));
    ac1 = fmaf(ac1, scl, fmaf(w0, x01, fmaf(w1, x11, fmaf(w2, x21, w3 * x31))));
    m = nm;
  }
  for (; e < end; ++e) {
    const int s0 = colt[e];
    unsigned int u0;
    __builtin_memcpy(&u0, xl + (size_t)s0 * FD + 2 * lane, 4);
    const float x00 = blo(u0), x01 = bhi(u0);
    float a0 = x00 + xr0, a1 = x01 + xr1;
    a0 = fmaxf(a0, 0.2f * a0); a1 = fmaxf(a1, 0.2f * a1);
    const float p0 = qsum32(fmaf(av.y, a1, av.x * a0));
    const float nm = fmaxf(m, p0);
    const float scl = fexp2(m - nm), w0 = fexp2(p0 - nm);
    den = fmaf(den, scl, w0);
    ac0 = fmaf(ac0, scl, w0 * x00);
    ac1 = fmaf(ac1, scl, w0 * x01);
    m = nm;
  }
  const float2 bv = ((const float2*)(bias + t * FD))[lane];
  const float rden = 1.f / den;
  sh0[tid] = fmaf(ac0, rden, bv.x);
  sh1[tid] = fmaf(ac1, rden, bv.y);
  __syncthreads();
  if (tid < 64) {
    float s0 = sh0[tid] + sh0[64 + tid] + sh0[128 + tid] + sh0[192 + tid];
    float s1 = sh1[tid] + sh1[64 + tid] + sh1[128 + tid] + sh1[192 + tid];
    if (mode == 0) {
      s0 = fmaxf(s0, 0.f); s1 = fmaxf(s1, 0.f);
      const unsigned short h0 = f2bf(s0), h1 = f2bf(s1);
      const unsigned short l0 = f2bf(s0 - bf2f(h0)), l1 = f2bf(s1 - bf2f(h1));
      ((unsigned int*)ahi)[(size_t)d * 64 + tid] = (unsigned)h0 | ((unsigned)h1 << 16);
      ((unsigned int*)alo)[(size_t)d * 64 + tid] = (unsigned)l0 | ((unsigned)l1 << 16);
    } else {
      // fused MLP head: h(128) -> relu(@W1+b1)(8) -> @W2+b2 (10)
      s0 = fmaxf(s0, 0.f); s1 = fmaxf(s1, 0.f);   // relu(h)
      const float4* wA = (const float4*)(W1 + tid * 16);  // rows 2*tid, 2*tid+1
      const float4 a0 = wA[0], a1 = wA[1], a2 = wA[2], a3 = wA[3];
      float z[8];
      z[0] = fmaf(s0, a0.x, s1 * a2.x); z[1] = fmaf(s0, a0.y, s1 * a2.y);
      z[2] = fmaf(s0, a0.z, s1 * a2.z); z[3] = fmaf(s0, a0.w, s1 * a2.w);
      z[4] = fmaf(s0, a1.x, s1 * a3.x); z[5] = fmaf(s0, a1.y, s1 * a3.y);
      z[6] = fmaf(s0, a1.z, s1 * a3.z); z[7] = fmaf(s0, a1.w, s1 * a3.w);
      #pragma unroll
      for (int j = 0; j < 8; ++j) {
        float v = qsum32(z[j]);          // 32-lane sums in each half
        v += __shfl_xor(v, 32, 64);      // cross-half: full 64-lane sum
        z[j] = fmaxf(v + b1v[j], 0.f);   // relu(z)
      }
      if (tid < 10) {
        float o = b2v[tid];
        #pragma unroll
        for (int j = 0; j < 8; ++j) o = fmaf(z[j], W2[j * 10 + tid], o);
        out[(size_t)d * 10 + tid] = o;
      }
    }
  }
}

extern "C" void kernel_launch(void* const* d_in, const int* in_sizes, int n_in,
                              void* d_out, int out_size, void* d_ws, size_t ws_size,
                              hipStream_t stream) {
  const float* x    = (const float*)d_in[0];
  const int*   ei   = (const int*)d_in[1];
  const float* Wl1  = (const float*)d_in[2];
  const float* Wr1  = (const float*)d_in[3];
  const float* att1 = (const float*)d_in[4];
  const float* b1   = (const float*)d_in[5];
  const float* Wl2  = (const float*)d_in[6];
  const float* Wr2  = (const float*)d_in[7];
  const float* att2 = (const float*)d_in[8];
  const float* b2   = (const float*)d_in[9];
  const float* Wi1  = (const float*)d_in[10];
  const float* bi1  = (const float*)d_in[11];
  const float* Wi2  = (const float*)d_in[12];
  const float* bi2  = (const float*)d_in[13];
  float* out = (float*)d_out;

  char* ws = (char*)d_ws;
  size_t off = 0;
  auto alloc = [&](size_t bytes) {
    void* p = ws + off;
    off = (off + bytes + 255) & ~(size_t)255;
    return p;
  };
  unsigned short* xl4   = (unsigned short*)alloc((size_t)TT * NN * FD * 2); // 51.2 MB
  unsigned short* xr4   = (unsigned short*)alloc((size_t)TT * NN * FD * 2); // 51.2 MB
  unsigned short* Ahi   = (unsigned short*)alloc((size_t)NN * FD * 2);      // 12.8 MB
  unsigned short* Alo   = (unsigned short*)alloc((size_t)NN * FD * 2);      // 12.8 MB
  unsigned short* Bpack = (unsigned short*)alloc((size_t)2 * TT * 2 * 16384 * 2); // 0.5 MB
  int*            col   = (int*)alloc((size_t)TT * EE * 4);                 // 6.4 MB
  int*            rowp  = (int*)alloc((size_t)TT * RPS * 4);                // 0.8 MB
  int*            bcur  = (int*)alloc((size_t)TT * NBKT * 4);
  int*            bbase = (int*)alloc((size_t)TT * NBKT * 4);
  unsigned int*   ebuf  = (unsigned int*)alloc((size_t)TT * NBKT * BCAP * 4); // 12.85 MB

  // --- CSR build (shared by both layers) ---
  hipMemsetAsync(bcur, 0, (size_t)TT * NBKT * 4, stream);
  k_cvtW<<<1024, 256, 0, stream>>>(Wl1, Wr1, Wl2, Wr2, Bpack);
  k_bucket<<<dim3(98, TT), 256, 0, stream>>>(ei, bcur, ebuf);
  k_bktscan<<<1, 1024, 0, stream>>>(bcur, bbase);
  k_scatter3<<<dim3(NBKT, TT), 256, 0, stream>>>(ebuf, bcur, bbase, rowp, col);

  // --- layer 1 ---
  k_cvtA<<<6250, 256, 0, stream>>>(x, Ahi, Alo);
  k_gemm4<<<dim3(782, TT), 128, 0, stream>>>(Ahi, Alo, Bpack, xl4, xr4);
  k_agg4<<<NN, 256, 0, stream>>>(xl4, xr4, col, rowp, att1, b1,
                                 Ahi, Alo, nullptr, nullptr, nullptr, nullptr,
                                 nullptr, 0);
  // --- layer 2 (MLP head fused into agg epilogue) ---
  k_gemm4<<<dim3(782, TT), 128, 0, stream>>>(Ahi, Alo, Bpack + (size_t)TT * 2 * 16384,
                                             xl4, xr4);
  k_agg4<<<NN, 256, 0, stream>>>(xl4, xr4, col, rowp, att2, b2,
                                 nullptr, nullptr, Wi1, bi1, Wi2, bi2,
                                 out, 1);
}